// Round 1
// baseline (2139.112 us; speedup 1.0000x reference)
//
#include <hip/hip_runtime.h>
#include <hip/hip_bf16.h>
#include <math.h>

// Fixed problem shape (from reference setup_inputs)
#define LL 4
#define BB 16
#define NN 4096
#define DD 1024
#define LDIM 4096   // LL*DD
#define KMAX 32     // capacity for k (actual k = 20)
#define KSELMAX 128 // capacity for k_sel = 5*k (actual 100)
#define KM_ITERS 10

// ---------------------------------------------------------------------------
// 1) score[b][n] = softmax(mean_l anomaly[l][b][n][:], axis=-1)[1]
// ---------------------------------------------------------------------------
__global__ __launch_bounds__(256) void score_kernel(const float* __restrict__ am,
                                                    float* __restrict__ score) {
    int idx = blockIdx.x * 256 + threadIdx.x;  // b*NN + n, grid covers BB*NN exactly
    float m0 = 0.f, m1 = 0.f;
#pragma unroll
    for (int l = 0; l < LL; ++l) {
        const float* p = am + ((size_t)l * BB * NN + idx) * 2;
        m0 += p[0];
        m1 += p[1];
    }
    m0 *= 0.25f;
    m1 *= 0.25f;
    float mx = fmaxf(m0, m1);
    float e0 = expf(m0 - mx), e1 = expf(m1 - mx);
    score[idx] = e1 / (e0 + e1);
}

// ---------------------------------------------------------------------------
// 2) exact stable top-k via rank: rank_i = #{j: s_j>s_i or (s_j==s_i and j<i)}
//    Strict total order -> ranks are a permutation; slot r gets exactly one i.
// ---------------------------------------------------------------------------
__global__ __launch_bounds__(256) void topk_kernel(const float* __restrict__ score,
                                                   const int* __restrict__ kp,
                                                   int* __restrict__ top_idx) {
    int b = blockIdx.y;
    int i = blockIdx.x * 256 + threadIdx.x;
    int k = *kp;
    int ksel = min(NN, 5 * k);
    __shared__ float s[NN];  // 16 KB
    const float* sb = score + (size_t)b * NN;
    for (int t = threadIdx.x; t < NN; t += 256) s[t] = sb[t];
    __syncthreads();
    float v = s[i];
    int rank = 0;
#pragma unroll 8
    for (int j = 0; j < NN; ++j) {
        float u = s[j];
        rank += (u > v) || (u == v && j < i);
    }
    if (rank < ksel) top_idx[b * KSELMAX + rank] = i;
}

// ---------------------------------------------------------------------------
// 3) gather x[b][j][l*DD+d] = patch[l][b][top_idx[b][j]][d]; also xx = |row|^2
// ---------------------------------------------------------------------------
__global__ __launch_bounds__(256) void gather_kernel(const float* __restrict__ pt,
                                                     const int* __restrict__ top_idx,
                                                     const int* __restrict__ kp,
                                                     float* __restrict__ x,
                                                     float* __restrict__ xx) {
    int b = blockIdx.y, j = blockIdx.x;
    int k = *kp, ksel = min(NN, 5 * k);
    if (j >= ksel) return;
    int idx = top_idx[b * KSELMAX + j];
    float4* xr = (float4*)(x + ((size_t)b * KSELMAX + j) * LDIM);
    float ss = 0.f;
#pragma unroll
    for (int l = 0; l < LL; ++l) {
        const float4* src = (const float4*)(pt + (((size_t)l * BB + b) * NN + idx) * DD);
        float4 v = src[threadIdx.x];  // DD/4 = 256 float4, one per thread
        xr[l * (DD / 4) + threadIdx.x] = v;
        ss += v.x * v.x + v.y * v.y + v.z * v.z + v.w * v.w;
    }
    __shared__ float red[4];
#pragma unroll
    for (int off = 32; off > 0; off >>= 1) ss += __shfl_xor(ss, off, 64);
    if ((threadIdx.x & 63) == 0) red[threadIdx.x >> 6] = ss;
    __syncthreads();
    if (threadIdx.x == 0) xx[b * KSELMAX + j] = red[0] + red[1] + red[2] + red[3];
}

// ---------------------------------------------------------------------------
// 4) init centers: c[b][kk] = x[b][trunc(kk * (ksel-1)/(k-1) in f32)]
//    (replicates jnp.linspace(0, ksel-1, k).astype(int32) in f32 math)
// ---------------------------------------------------------------------------
__global__ __launch_bounds__(256) void init_centers_kernel(const float* __restrict__ x,
                                                           const int* __restrict__ kp,
                                                           float* __restrict__ c,
                                                           float* __restrict__ cc) {
    int b = blockIdx.y, kk = blockIdx.x;
    int k = *kp, ksel = min(NN, 5 * k);
    if (kk >= k) return;
    float step = (k > 1) ? ((float)(ksel - 1) / (float)(k - 1)) : 0.f;
    int src = (int)((float)kk * step);
    const float4* xr = (const float4*)(x + ((size_t)b * KSELMAX + src) * LDIM);
    float4* cr = (float4*)(c + ((size_t)b * KMAX + kk) * LDIM);
    float ss = 0.f;
#pragma unroll
    for (int i = 0; i < 4; ++i) {
        float4 v = xr[threadIdx.x + 256 * i];
        cr[threadIdx.x + 256 * i] = v;
        ss += v.x * v.x + v.y * v.y + v.z * v.z + v.w * v.w;
    }
    __shared__ float red[4];
#pragma unroll
    for (int off = 32; off > 0; off >>= 1) ss += __shfl_xor(ss, off, 64);
    if ((threadIdx.x & 63) == 0) red[threadIdx.x >> 6] = ss;
    __syncthreads();
    if (threadIdx.x == 0) cc[b * KMAX + kk] = red[0] + red[1] + red[2] + red[3];
}

// ---------------------------------------------------------------------------
// 5) assign: labels[b][j] = argmin_k (xx[j] - 2 x_j.c_k + cc[k]), first-min tie
//    2 points per block; x rows staged in LDS; wave w handles clusters w,w+4,...
// ---------------------------------------------------------------------------
__global__ __launch_bounds__(256) void assign_kernel(const float* __restrict__ x,
                                                     const float* __restrict__ xx,
                                                     const float* __restrict__ c,
                                                     const float* __restrict__ cc,
                                                     const int* __restrict__ kp,
                                                     int* __restrict__ labels) {
    int b = blockIdx.y, pr = blockIdx.x;
    int k = *kp, ksel = min(NN, 5 * k);
    int j0 = pr * 2, j1 = pr * 2 + 1;
    if (j0 >= ksel) return;
    bool has1 = (j1 < ksel);
    int j1c = has1 ? j1 : j0;

    __shared__ float4 xs[2][LDIM / 4];  // 32 KB
    __shared__ float dist[2][KMAX];

    const float4* x0 = (const float4*)(x + ((size_t)b * KSELMAX + j0) * LDIM);
    const float4* x1 = (const float4*)(x + ((size_t)b * KSELMAX + j1c) * LDIM);
    for (int t = threadIdx.x; t < LDIM / 4; t += 256) {
        xs[0][t] = x0[t];
        xs[1][t] = x1[t];
    }
    __syncthreads();

    int wave = threadIdx.x >> 6, lane = threadIdx.x & 63;
    float xx0 = xx[b * KSELMAX + j0];
    float xx1 = xx[b * KSELMAX + j1c];
    for (int kk = wave; kk < k; kk += 4) {
        const float4* cr = (const float4*)(c + ((size_t)b * KMAX + kk) * LDIM);
        float a0 = 0.f, a1 = 0.f;
#pragma unroll
        for (int i = 0; i < 16; ++i) {  // 4096/4/64 = 16 float4 per lane
            float4 cv = cr[lane + 64 * i];
            float4 v0 = xs[0][lane + 64 * i];
            float4 v1 = xs[1][lane + 64 * i];
            a0 += cv.x * v0.x + cv.y * v0.y + cv.z * v0.z + cv.w * v0.w;
            a1 += cv.x * v1.x + cv.y * v1.y + cv.z * v1.z + cv.w * v1.w;
        }
#pragma unroll
        for (int off = 32; off > 0; off >>= 1) {
            a0 += __shfl_xor(a0, off, 64);
            a1 += __shfl_xor(a1, off, 64);
        }
        if (lane == 0) {
            float ccv = cc[b * KMAX + kk];
            dist[0][kk] = xx0 - 2.f * a0 + ccv;
            dist[1][kk] = xx1 - 2.f * a1 + ccv;
        }
    }
    __syncthreads();
    if (threadIdx.x == 0) {
        int best = 0;
        float bv = dist[0][0];
        for (int kk = 1; kk < k; ++kk) {
            float d = dist[0][kk];
            if (d < bv) { bv = d; best = kk; }
        }
        labels[b * KSELMAX + j0] = best;
    }
    if (threadIdx.x == 64 && has1) {
        int best = 0;
        float bv = dist[1][0];
        for (int kk = 1; kk < k; ++kk) {
            float d = dist[1][kk];
            if (d < bv) { bv = d; best = kk; }
        }
        labels[b * KSELMAX + j1] = best;
    }
}

// ---------------------------------------------------------------------------
// 6) update: c[b][kk] = mean of x rows with label kk (fixed order n ascending);
//    skip entirely when count==0 (old center + cc preserved, matching where()).
// ---------------------------------------------------------------------------
__global__ __launch_bounds__(256) void update_kernel(const float* __restrict__ x,
                                                     const int* __restrict__ labels,
                                                     const int* __restrict__ kp,
                                                     float* __restrict__ c,
                                                     float* __restrict__ cc) {
    int b = blockIdx.y, kk = blockIdx.x;
    int k = *kp, ksel = min(NN, 5 * k);
    if (kk >= k) return;
    __shared__ int lab[KSELMAX];
    for (int t = threadIdx.x; t < ksel; t += 256) lab[t] = labels[b * KSELMAX + t];
    __syncthreads();

    float4 acc[4];
#pragma unroll
    for (int i = 0; i < 4; ++i) acc[i] = make_float4(0.f, 0.f, 0.f, 0.f);
    int cnt = 0;
    for (int n = 0; n < ksel; ++n) {
        if (lab[n] == kk) {
            ++cnt;
            const float4* xr = (const float4*)(x + ((size_t)b * KSELMAX + n) * LDIM);
#pragma unroll
            for (int i = 0; i < 4; ++i) {
                float4 v = xr[threadIdx.x + 256 * i];
                acc[i].x += v.x;
                acc[i].y += v.y;
                acc[i].z += v.z;
                acc[i].w += v.w;
            }
        }
    }
    if (cnt == 0) return;  // uniform across block
    float inv = 1.f / (float)cnt;
    float4* cr = (float4*)(c + ((size_t)b * KMAX + kk) * LDIM);
    float ss = 0.f;
#pragma unroll
    for (int i = 0; i < 4; ++i) {
        float4 v = make_float4(acc[i].x * inv, acc[i].y * inv, acc[i].z * inv, acc[i].w * inv);
        cr[threadIdx.x + 256 * i] = v;
        ss += v.x * v.x + v.y * v.y + v.z * v.z + v.w * v.w;
    }
    __shared__ float red[4];
#pragma unroll
    for (int off = 32; off > 0; off >>= 1) ss += __shfl_xor(ss, off, 64);
    if ((threadIdx.x & 63) == 0) red[threadIdx.x >> 6] = ss;
    __syncthreads();
    if (threadIdx.x == 0) cc[b * KMAX + kk] = red[0] + red[1] + red[2] + red[3];
}

// ---------------------------------------------------------------------------
// 7) output: out[b][d] = (1/k) * sum_n avg_tok[n][d] / cnt[lab[n]], normalized.
//    (sum_k segment-mean == sum_n tok_n * invcnt[lab_n]; empty clusters add 0)
// ---------------------------------------------------------------------------
__global__ __launch_bounds__(1024) void output_kernel(const float* __restrict__ x,
                                                      const int* __restrict__ labels,
                                                      const int* __restrict__ kp,
                                                      float* __restrict__ out) {
    int b = blockIdx.x;
    int d = threadIdx.x;  // 0..1023
    int k = *kp, ksel = min(NN, 5 * k);
    __shared__ int lab[KSELMAX];
    __shared__ float invcnt[KMAX];
    __shared__ float red[16];
    __shared__ float norm_s;
    if (d < ksel) lab[d] = labels[b * KSELMAX + d];
    __syncthreads();
    if (d < k) {
        int c = 0;
        for (int n = 0; n < ksel; ++n) c += (lab[n] == d);
        invcnt[d] = (c > 0) ? (1.f / (float)c) : 0.f;
    }
    __syncthreads();
    float acc = 0.f;
    const float* xb = x + (size_t)b * KSELMAX * LDIM;
    for (int n = 0; n < ksel; ++n) {
        const float* xr = xb + (size_t)n * LDIM;
        float tok = (xr[d] + xr[DD + d] + xr[2 * DD + d] + xr[3 * DD + d]) * 0.25f;
        acc += tok * invcnt[lab[n]];
    }
    acc /= (float)k;
    float ss = acc * acc;
#pragma unroll
    for (int off = 32; off > 0; off >>= 1) ss += __shfl_xor(ss, off, 64);
    if ((d & 63) == 0) red[d >> 6] = ss;
    __syncthreads();
    if (d == 0) {
        float t = 0.f;
        for (int i = 0; i < 16; ++i) t += red[i];
        norm_s = fmaxf(sqrtf(t), 1e-12f);
    }
    __syncthreads();
    out[b * DD + d] = acc / norm_s;
}

// ---------------------------------------------------------------------------
extern "C" void kernel_launch(void* const* d_in, const int* in_sizes, int n_in,
                              void* d_out, int out_size, void* d_ws, size_t ws_size,
                              hipStream_t stream) {
    const float* pt = (const float*)d_in[0];
    const float* am = (const float*)d_in[1];
    const int* kp = (const int*)d_in[2];
    float* out = (float*)d_out;

    char* w = (char*)d_ws;
    float* score = (float*)w;   w += (size_t)BB * NN * 4;
    int* top_idx = (int*)w;     w += (size_t)BB * KSELMAX * 4;
    float* x = (float*)w;       w += (size_t)BB * KSELMAX * LDIM * 4;
    float* xx = (float*)w;      w += (size_t)BB * KSELMAX * 4;
    float* c = (float*)w;       w += (size_t)BB * KMAX * LDIM * 4;
    float* cc = (float*)w;      w += (size_t)BB * KMAX * 4;
    int* labels = (int*)w;      w += (size_t)BB * KSELMAX * 4;

    score_kernel<<<dim3(BB * NN / 256), 256, 0, stream>>>(am, score);
    topk_kernel<<<dim3(NN / 256, BB), 256, 0, stream>>>(score, kp, top_idx);
    gather_kernel<<<dim3(KSELMAX, BB), 256, 0, stream>>>(pt, top_idx, kp, x, xx);
    init_centers_kernel<<<dim3(KMAX, BB), 256, 0, stream>>>(x, kp, c, cc);
    for (int it = 0; it < KM_ITERS; ++it) {
        assign_kernel<<<dim3(KSELMAX / 2, BB), 256, 0, stream>>>(x, xx, c, cc, kp, labels);
        update_kernel<<<dim3(KMAX, BB), 256, 0, stream>>>(x, labels, kp, c, cc);
    }
    assign_kernel<<<dim3(KSELMAX / 2, BB), 256, 0, stream>>>(x, xx, c, cc, kp, labels);
    output_kernel<<<dim3(BB), 1024, 0, stream>>>(x, labels, kp, out);
}